// Round 1
// baseline (1088.100 us; speedup 1.0000x reference)
//
#include <hip/hip_runtime.h>
#include <math.h>

#define BB 64
#define CC 2048
#define MM 196
#define DD 256
#define NTOT (BB * MM)  // 12544

// ---------------------------------------------------------------------------
// K1: 1x1 conv + BN(eval) + ReLU.  GEMM: W[256x2048] * X[b][2048x196].
// Block tile 128d x 128n (n = b*196+m flattened), 256 threads, 8x8/thread,
// KC=16, register prefetch of next K-chunk to hide global latency.
// Output TRANSPOSED: yt[b][m][d] (d contiguous) for downstream coalescing.
// ---------------------------------------------------------------------------
__global__ __launch_bounds__(256) void k_conv(
    const float* __restrict__ x, const float* __restrict__ w,
    const float* __restrict__ gamma, const float* __restrict__ beta,
    const float* __restrict__ rmean, const float* __restrict__ rvar,
    float* __restrict__ yt) {
  const int tid = threadIdx.x;
  const int tx = tid & 15;   // n-group
  const int ty = tid >> 4;   // d-group
  const int n0 = blockIdx.x * 128;
  const int d0 = blockIdx.y * 128;

  __shared__ float Ws[16][132];  // [k][d], pad 132 to break write conflicts
  __shared__ float Xs[16][128];  // [k][n]

  float acc[8][8];
#pragma unroll
  for (int i = 0; i < 8; ++i)
#pragma unroll
    for (int j = 0; j < 8; ++j) acc[i][j] = 0.f;

  // staging assignments
  const int cW = tid & 15;   // k within chunk for W
  const int dW = tid >> 4;   // d base (+16p)
  const int nX = tid & 127;  // n within tile
  const int cX = tid >> 7;   // k base (+2p)
  const int gn = n0 + nX;
  const int bX = gn / MM;
  const int mX = gn - bX * MM;
  const float* xptr = x + (size_t)bX * CC * MM + mX;

  float wreg[8], xreg[8];
#pragma unroll
  for (int p = 0; p < 8; ++p)
    wreg[p] = w[(size_t)(d0 + dW + p * 16) * CC + cW];
#pragma unroll
  for (int p = 0; p < 8; ++p)
    xreg[p] = xptr[(size_t)(cX + p * 2) * MM];

  for (int k0 = 0; k0 < CC; k0 += 16) {
    __syncthreads();
#pragma unroll
    for (int p = 0; p < 8; ++p) Ws[cW][dW + p * 16] = wreg[p];
#pragma unroll
    for (int p = 0; p < 8; ++p) Xs[cX + p * 2][nX] = xreg[p];
    __syncthreads();
    if (k0 + 16 < CC) {  // prefetch next chunk; latency overlaps compute below
#pragma unroll
      for (int p = 0; p < 8; ++p)
        wreg[p] = w[(size_t)(d0 + dW + p * 16) * CC + (k0 + 16) + cW];
#pragma unroll
      for (int p = 0; p < 8; ++p)
        xreg[p] = xptr[(size_t)(k0 + 16 + cX + p * 2) * MM];
    }
#pragma unroll
    for (int k = 0; k < 16; ++k) {
      float a[8], bv[8];
#pragma unroll
      for (int i = 0; i < 8; ++i) a[i] = Ws[k][ty * 8 + i];
#pragma unroll
      for (int j = 0; j < 8; ++j) bv[j] = Xs[k][tx * 8 + j];
#pragma unroll
      for (int i = 0; i < 8; ++i)
#pragma unroll
        for (int j = 0; j < 8; ++j) acc[i][j] = fmaf(a[i], bv[j], acc[i][j]);
    }
  }

  // BN (eval, running stats) + ReLU epilogue, store transposed yt[b][m][d]
  float scl[8], sft[8];
#pragma unroll
  for (int i = 0; i < 8; ++i) {
    int d = d0 + ty * 8 + i;
    float s = gamma[d] / sqrtf(rvar[d] + 1e-5f);
    scl[i] = s;
    sft[i] = beta[d] - rmean[d] * s;
  }
#pragma unroll
  for (int j = 0; j < 8; ++j) {
    int n = n0 + tx * 8 + j;
    int b = n / MM;
    int m = n - b * MM;
    float* yrow = yt + ((size_t)b * MM + m) * DD + d0 + ty * 8;
#pragma unroll
    for (int i = 0; i < 8; ++i) {
      float v = fmaf(acc[i][j], scl[i], sft[i]);
      yrow[i] = v > 0.f ? v : 0.f;
    }
  }
}

// ---------------------------------------------------------------------------
// K2: per-(b,d) mean over m in fp64.  yt is d-contiguous -> coalesced.
// ---------------------------------------------------------------------------
__global__ __launch_bounds__(256) void k_means(const float* __restrict__ yt,
                                               double* __restrict__ mean) {
  const int b = blockIdx.x;
  const int d = threadIdx.x;
  const float* p = yt + (size_t)b * MM * DD + d;
  double s0 = 0, s1 = 0, s2 = 0, s3 = 0;
  for (int m = 0; m < MM; m += 4) {  // 196 % 4 == 0
    s0 += (double)p[(size_t)(m + 0) * DD];
    s1 += (double)p[(size_t)(m + 1) * DD];
    s2 += (double)p[(size_t)(m + 2) * DD];
    s3 += (double)p[(size_t)(m + 3) * DD];
  }
  mean[b * DD + d] = (s0 + s1 + s2 + s3) * (1.0 / MM);
}

// ---------------------------------------------------------------------------
// K3: cov[b] = (Y-mu)(Y-mu)^T / M + eps*I  in fp64.  Lower 64x64 tiles only
// (10 per batch), mirrored on store.  256 thr, 4x4 fp64 per thread, KC=32.
// ---------------------------------------------------------------------------
__global__ __launch_bounds__(256) void k_cov(const float* __restrict__ yt,
                                             const double* __restrict__ mean,
                                             double* __restrict__ cov) {
  const int b = blockIdx.x;
  const int t = blockIdx.y;  // 0..9 -> (ti >= tj)
  const int ti = (t < 1) ? 0 : (t < 3) ? 1 : (t < 6) ? 2 : 3;
  const int tj = t - (ti * (ti + 1)) / 2;
  const int i0 = ti * 64, j0 = tj * 64;
  const int tid = threadIdx.x;
  const int tx = tid & 15, ty = tid >> 4;

  __shared__ double As[32][66];  // [k][i] (pad 66)
  __shared__ double Bs[32][66];

  double acc[4][4];
#pragma unroll
  for (int i = 0; i < 4; ++i)
#pragma unroll
    for (int j = 0; j < 4; ++j) acc[i][j] = 0.0;

  const int dl = tid & 63, kl = tid >> 6;  // kl in 0..3
  const double mA = mean[b * DD + i0 + dl];
  const double mB = mean[b * DD + j0 + dl];
  const float* ybase = yt + (size_t)b * MM * DD;

  for (int k0 = 0; k0 < MM; k0 += 32) {  // 7 chunks, last has 4 valid
    __syncthreads();
#pragma unroll
    for (int p = 0; p < 8; ++p) {
      int k = kl + p * 4;
      int m = k0 + k;
      double av = 0.0, bv = 0.0;
      if (m < MM) {
        av = (double)ybase[(size_t)m * DD + i0 + dl] - mA;
        bv = (double)ybase[(size_t)m * DD + j0 + dl] - mB;
      }
      As[k][dl] = av;
      Bs[k][dl] = bv;
    }
    __syncthreads();
#pragma unroll
    for (int k = 0; k < 32; ++k) {
      double a[4], bv[4];
#pragma unroll
      for (int i = 0; i < 4; ++i) a[i] = As[k][ty * 4 + i];
#pragma unroll
      for (int j = 0; j < 4; ++j) bv[j] = Bs[k][tx * 4 + j];
#pragma unroll
      for (int i = 0; i < 4; ++i)
#pragma unroll
        for (int j = 0; j < 4; ++j) acc[i][j] = fma(a[i], bv[j], acc[i][j]);
    }
  }

  double* cb = cov + (size_t)b * DD * DD;
#pragma unroll
  for (int i = 0; i < 4; ++i) {
#pragma unroll
    for (int j = 0; j < 4; ++j) {
      int gi = i0 + ty * 4 + i, gj = j0 + tx * 4 + j;
      double v = acc[i][j] * (1.0 / MM);
      if (gi == gj) v += 1e-6;
      cb[(size_t)gi * DD + gj] = v;
      if (ti != tj) cb[(size_t)gj * DD + gi] = v;
    }
  }
}

// ---------------------------------------------------------------------------
// K4: blocked Cholesky (lower), one block per matrix, NB=32 panel in LDS.
// Pivots go to a separate array so the factor loop needs only 2 syncs/col.
// Trailing A22 -= L21*L21^T as 4x4-register LDS-GEMM with global RMW
// (lower half only; upper half of cov is stale-but-never-read).
// ---------------------------------------------------------------------------
__global__ __launch_bounds__(256) void k_chol(double* __restrict__ cov) {
  const int b = blockIdx.x;
  double* A = cov + (size_t)b * DD * DD;
  const int tid = threadIdx.x;
  __shared__ double P[256 * 33];  // panel rows x 32 (pad 33)
  __shared__ double pivs[32];

  for (int kb = 0; kb < 8; ++kb) {
    const int j0 = kb * 32;
    const int rows = DD - j0;
    // load panel: rows j0..255, cols j0..j0+31 (coalesced)
    for (int e = tid; e < rows * 32; e += 256) {
      int r = e >> 5, c = e & 31;
      P[r * 33 + c] = A[(size_t)(j0 + r) * DD + j0 + c];
    }
    __syncthreads();
    // factor 32 columns (fused diag factor + panel solve)
    for (int j = 0; j < 32; ++j) {
      double piv = sqrt(P[j * 33 + j]);  // no thread writes P[j][j] -> no race
      double rpiv = 1.0 / piv;
      if (tid == 0) pivs[j] = piv;
      for (int i = j + 1 + tid; i < rows; i += 256) P[i * 33 + j] *= rpiv;
      __syncthreads();
      for (int i = j + 1 + tid; i < rows; i += 256) {
        double lij = P[i * 33 + j];
        for (int jj = j + 1; jj < 32; ++jj)
          P[i * 33 + jj] -= lij * P[jj * 33 + j];
      }
      __syncthreads();
    }
    // write back L panel (lower part only)
    for (int e = tid; e < rows * 32; e += 256) {
      int r = e >> 5, c = e & 31;
      if (r >= c)
        A[(size_t)(j0 + r) * DD + j0 + c] = (r == c) ? pivs[c] : P[r * 33 + c];
    }
    // trailing update
    const int T = rows - 32;
    if (T > 0) {
      const int nt = (T + 63) >> 6;
      const int txl = tid & 15, tyl = tid >> 4;
      for (int tI = 0; tI < nt; ++tI)
        for (int tJ = 0; tJ <= tI; ++tJ) {
          const int bi = tI * 64 + tyl * 4;
          const int bj = tJ * 64 + txl * 4;
          const double* Pa[4];
          const double* Pb[4];
#pragma unroll
          for (int q = 0; q < 4; ++q) {
            int ri = bi + q;
            if (ri >= T) ri = T - 1;  // clamp; result discarded by store guard
            int rj = bj + q;
            if (rj >= T) rj = T - 1;
            Pa[q] = &P[(32 + ri) * 33];
            Pb[q] = &P[(32 + rj) * 33];
          }
          double s[4][4];
#pragma unroll
          for (int i = 0; i < 4; ++i)
#pragma unroll
            for (int j = 0; j < 4; ++j) s[i][j] = 0.0;
#pragma unroll
          for (int p = 0; p < 32; ++p) {
            double bv[4];
#pragma unroll
            for (int j = 0; j < 4; ++j) bv[j] = Pb[j][p];
#pragma unroll
            for (int i = 0; i < 4; ++i) {
              double av = Pa[i][p];
#pragma unroll
              for (int j = 0; j < 4; ++j) s[i][j] = fma(av, bv[j], s[i][j]);
            }
          }
#pragma unroll
          for (int i = 0; i < 4; ++i)
#pragma unroll
            for (int j = 0; j < 4; ++j) {
              int gi = bi + i, gj = bj + j;
              if (gi < T && gj < T && gi >= gj)
                A[(size_t)(j0 + 32 + gi) * DD + (j0 + 32 + gj)] -= s[i][j];
            }
        }
    }
    __syncthreads();  // A22 RMW + P reads done before next panel load
  }
}

// ---------------------------------------------------------------------------
// K5: out[b, triu(i,j)] = (i==j) ? 2*log(L[ii]) : L[j][i], fp32.
// ---------------------------------------------------------------------------
__global__ __launch_bounds__(256) void k_out(const double* __restrict__ cov,
                                             float* __restrict__ out) {
  const int b = blockIdx.y;
  const int ij = blockIdx.x * 256 + threadIdx.x;
  const int i = ij >> 8, j = ij & 255;
  if (j < i) return;
  const double* A = cov + (size_t)b * DD * DD;
  double v;
  if (i == j)
    v = 2.0 * log(A[(size_t)i * DD + i]);
  else
    v = A[(size_t)j * DD + i];
  const int off = i * DD - (i * (i - 1)) / 2 + (j - i);
  out[(size_t)b * 32896 + off] = (float)v;
}

extern "C" void kernel_launch(void* const* d_in, const int* in_sizes, int n_in,
                              void* d_out, int out_size, void* d_ws,
                              size_t ws_size, hipStream_t stream) {
  const float* x = (const float*)d_in[0];
  const float* w = (const float*)d_in[1];
  const float* gamma = (const float*)d_in[2];
  const float* beta = (const float*)d_in[3];
  const float* rmean = (const float*)d_in[4];
  const float* rvar = (const float*)d_in[5];
  float* out = (float*)d_out;

  char* ws = (char*)d_ws;
  float* yt = (float*)ws;                               // 64*196*256*4 = 12,845,056 B
  double* mean = (double*)(ws + 12845056);              // 64*256*8     =    131,072 B
  double* cov = (double*)(ws + 12845056 + 131072);      // 64*256*256*8 = 33,554,432 B

  k_conv<<<dim3(NTOT / 128, DD / 128), 256, 0, stream>>>(x, w, gamma, beta,
                                                         rmean, rvar, yt);
  k_means<<<BB, 256, 0, stream>>>(yt, mean);
  k_cov<<<dim3(BB, 10), 256, 0, stream>>>(yt, mean, cov);
  k_chol<<<BB, 256, 0, stream>>>(cov);
  k_out<<<dim3(DD * DD / 256, BB), 256, 0, stream>>>(cov, out);
}

// Round 2
// 797.538 us; speedup vs baseline: 1.3643x; 1.3643x over previous
//
#include <hip/hip_runtime.h>
#include <math.h>

#define BB 64
#define CC 2048
#define MM 196
#define DD 256
#define NTOT (BB * MM)  // 12544

// ---------------------------------------------------------------------------
// K1: 1x1 conv + BN(eval) + ReLU.  GEMM: W[256x2048] * X[b][2048x196].
// Block tile 128d x 128n (n = b*196+m flattened), 256 threads, 8x8/thread,
// KC=16, register prefetch of next K-chunk to hide global latency.
// Output TRANSPOSED: yt[b][m][d] (d contiguous) for downstream coalescing.
// ---------------------------------------------------------------------------
__global__ __launch_bounds__(256) void k_conv(
    const float* __restrict__ x, const float* __restrict__ w,
    const float* __restrict__ gamma, const float* __restrict__ beta,
    const float* __restrict__ rmean, const float* __restrict__ rvar,
    float* __restrict__ yt) {
  const int tid = threadIdx.x;
  const int tx = tid & 15;   // n-group
  const int ty = tid >> 4;   // d-group
  const int n0 = blockIdx.x * 128;
  const int d0 = blockIdx.y * 128;

  __shared__ float Ws[16][132];  // [k][d], pad 132 to break write conflicts
  __shared__ float Xs[16][128];  // [k][n]

  float acc[8][8];
#pragma unroll
  for (int i = 0; i < 8; ++i)
#pragma unroll
    for (int j = 0; j < 8; ++j) acc[i][j] = 0.f;

  // staging assignments
  const int cW = tid & 15;   // k within chunk for W
  const int dW = tid >> 4;   // d base (+16p)
  const int nX = tid & 127;  // n within tile
  const int cX = tid >> 7;   // k base (+2p)
  const int gn = n0 + nX;
  const int bX = gn / MM;
  const int mX = gn - bX * MM;
  const float* xptr = x + (size_t)bX * CC * MM + mX;

  float wreg[8], xreg[8];
#pragma unroll
  for (int p = 0; p < 8; ++p)
    wreg[p] = w[(size_t)(d0 + dW + p * 16) * CC + cW];
#pragma unroll
  for (int p = 0; p < 8; ++p)
    xreg[p] = xptr[(size_t)(cX + p * 2) * MM];

  for (int k0 = 0; k0 < CC; k0 += 16) {
    __syncthreads();
#pragma unroll
    for (int p = 0; p < 8; ++p) Ws[cW][dW + p * 16] = wreg[p];
#pragma unroll
    for (int p = 0; p < 8; ++p) Xs[cX + p * 2][nX] = xreg[p];
    __syncthreads();
    if (k0 + 16 < CC) {  // prefetch next chunk; latency overlaps compute below
#pragma unroll
      for (int p = 0; p < 8; ++p)
        wreg[p] = w[(size_t)(d0 + dW + p * 16) * CC + (k0 + 16) + cW];
#pragma unroll
      for (int p = 0; p < 8; ++p)
        xreg[p] = xptr[(size_t)(k0 + 16 + cX + p * 2) * MM];
    }
#pragma unroll
    for (int k = 0; k < 16; ++k) {
      float a[8], bv[8];
#pragma unroll
      for (int i = 0; i < 8; ++i) a[i] = Ws[k][ty * 8 + i];
#pragma unroll
      for (int j = 0; j < 8; ++j) bv[j] = Xs[k][tx * 8 + j];
#pragma unroll
      for (int i = 0; i < 8; ++i)
#pragma unroll
        for (int j = 0; j < 8; ++j) acc[i][j] = fmaf(a[i], bv[j], acc[i][j]);
    }
  }

  // BN (eval, running stats) + ReLU epilogue, store transposed yt[b][m][d]
  float scl[8], sft[8];
#pragma unroll
  for (int i = 0; i < 8; ++i) {
    int d = d0 + ty * 8 + i;
    float s = gamma[d] / sqrtf(rvar[d] + 1e-5f);
    scl[i] = s;
    sft[i] = beta[d] - rmean[d] * s;
  }
#pragma unroll
  for (int j = 0; j < 8; ++j) {
    int n = n0 + tx * 8 + j;
    int b = n / MM;
    int m = n - b * MM;
    float* yrow = yt + ((size_t)b * MM + m) * DD + d0 + ty * 8;
#pragma unroll
    for (int i = 0; i < 8; ++i) {
      float v = fmaf(acc[i][j], scl[i], sft[i]);
      yrow[i] = v > 0.f ? v : 0.f;
    }
  }
}

// ---------------------------------------------------------------------------
// K2: per-(b,d) mean over m in fp64.  yt is d-contiguous -> coalesced.
// ---------------------------------------------------------------------------
__global__ __launch_bounds__(256) void k_means(const float* __restrict__ yt,
                                               double* __restrict__ mean) {
  const int b = blockIdx.x;
  const int d = threadIdx.x;
  const float* p = yt + (size_t)b * MM * DD + d;
  double s0 = 0, s1 = 0, s2 = 0, s3 = 0;
  for (int m = 0; m < MM; m += 4) {  // 196 % 4 == 0
    s0 += (double)p[(size_t)(m + 0) * DD];
    s1 += (double)p[(size_t)(m + 1) * DD];
    s2 += (double)p[(size_t)(m + 2) * DD];
    s3 += (double)p[(size_t)(m + 3) * DD];
  }
  mean[b * DD + d] = (s0 + s1 + s2 + s3) * (1.0 / MM);
}

// ---------------------------------------------------------------------------
// K3: cov[b] = (Y-mu)(Y-mu)^T / M + eps*I  in fp64.  Lower 64x64 tiles only
// (10 per batch), mirrored on store.  256 thr, 4x4 fp64 per thread, KC=32.
// ---------------------------------------------------------------------------
__global__ __launch_bounds__(256) void k_cov(const float* __restrict__ yt,
                                             const double* __restrict__ mean,
                                             double* __restrict__ cov) {
  const int b = blockIdx.x;
  const int t = blockIdx.y;  // 0..9 -> (ti >= tj)
  const int ti = (t < 1) ? 0 : (t < 3) ? 1 : (t < 6) ? 2 : 3;
  const int tj = t - (ti * (ti + 1)) / 2;
  const int i0 = ti * 64, j0 = tj * 64;
  const int tid = threadIdx.x;
  const int tx = tid & 15, ty = tid >> 4;

  __shared__ double As[32][66];  // [k][i] (pad 66)
  __shared__ double Bs[32][66];

  double acc[4][4];
#pragma unroll
  for (int i = 0; i < 4; ++i)
#pragma unroll
    for (int j = 0; j < 4; ++j) acc[i][j] = 0.0;

  const int dl = tid & 63, kl = tid >> 6;  // kl in 0..3
  const double mA = mean[b * DD + i0 + dl];
  const double mB = mean[b * DD + j0 + dl];
  const float* ybase = yt + (size_t)b * MM * DD;

  for (int k0 = 0; k0 < MM; k0 += 32) {  // 7 chunks, last has 4 valid
    __syncthreads();
#pragma unroll
    for (int p = 0; p < 8; ++p) {
      int k = kl + p * 4;
      int m = k0 + k;
      double av = 0.0, bv = 0.0;
      if (m < MM) {
        av = (double)ybase[(size_t)m * DD + i0 + dl] - mA;
        bv = (double)ybase[(size_t)m * DD + j0 + dl] - mB;
      }
      As[k][dl] = av;
      Bs[k][dl] = bv;
    }
    __syncthreads();
#pragma unroll
    for (int k = 0; k < 32; ++k) {
      double a[4], bv[4];
#pragma unroll
      for (int i = 0; i < 4; ++i) a[i] = As[k][ty * 4 + i];
#pragma unroll
      for (int j = 0; j < 4; ++j) bv[j] = Bs[k][tx * 4 + j];
#pragma unroll
      for (int i = 0; i < 4; ++i)
#pragma unroll
        for (int j = 0; j < 4; ++j) acc[i][j] = fma(a[i], bv[j], acc[i][j]);
    }
  }

  double* cb = cov + (size_t)b * DD * DD;
#pragma unroll
  for (int i = 0; i < 4; ++i) {
#pragma unroll
    for (int j = 0; j < 4; ++j) {
      int gi = i0 + ty * 4 + i, gj = j0 + tx * 4 + j;
      double v = acc[i][j] * (1.0 / MM);
      if (gi == gj) v += 1e-6;
      cb[(size_t)gi * DD + gj] = v;
      if (ti != tj) cb[(size_t)gj * DD + gi] = v;
    }
  }
}

// ---------------------------------------------------------------------------
// K4a: panel factor for panel kb (cols j0..j0+31).
//  - wave 0 lanes 0..31: 32x32 diag Cholesky entirely in registers via
//    __shfl column broadcasts (zero barriers).
//  - waves 1..3: concurrently stage A21 (rows below diag) into LDS.
//  - one __syncthreads, then all 256 threads do the triangular solve
//    L21 = A21 * L11^-T with each thread's row held in registers
//    (zero barriers; L11 read from LDS as wave-uniform broadcasts).
// ---------------------------------------------------------------------------
__global__ __launch_bounds__(256) void k_panel(double* __restrict__ cov,
                                               int kb) {
  const int b = blockIdx.x;
  double* A = cov + (size_t)b * DD * DD;
  const int j0 = kb * 32;
  const int T = DD - j0 - 32;  // rows below the diag block
  const int tid = threadIdx.x;

  __shared__ double L11s[32][33];
  __shared__ double rpivs[32];
  __shared__ double Ps[224][33];  // A21 staging (max T = 224)

  if (tid >= 64) {
    // waves 1..3: stage A21 into LDS (coalesced rows)
    for (int e = tid - 64; e < T * 32; e += 192) {
      int r = e >> 5, c = e & 31;
      Ps[r][c] = A[(size_t)(j0 + 32 + r) * DD + j0 + c];
    }
  } else if (tid < 32) {
    // diag block factor in registers, wave-synchronous (half of wave 0)
    double r[32];
#pragma unroll
    for (int k = 0; k < 32; ++k) r[k] = A[(size_t)(j0 + tid) * DD + j0 + k];
    double rpkeep = 0.0;
#pragma unroll
    for (int j = 0; j < 32; ++j) {
      double dj = __shfl(r[j], j);  // current pivot value from lane j
      double piv = sqrt(dj);
      double rp = 1.0 / piv;
      if (tid == j) {
        r[j] = piv;
        rpkeep = rp;
      } else {
        r[j] = r[j] * rp;  // lanes < j update junk; harmless
      }
      double lij = r[j];
#pragma unroll
      for (int k = j + 1; k < 32; ++k) {
        double ck = __shfl(lij, k);  // L[k][j] from lane k
        r[k] -= lij * ck;            // junk region for lanes <= j; harmless
      }
    }
    // publish L11 + reciprocal pivots, and write back to global (lower)
#pragma unroll
    for (int k = 0; k < 32; ++k) L11s[tid][k] = (k <= tid) ? r[k] : 0.0;
    rpivs[tid] = rpkeep;
    for (int k = 0; k <= tid; ++k)
      A[(size_t)(j0 + tid) * DD + j0 + k] = r[k];
  }
  __syncthreads();

  // TRSM: each thread owns one row of L21 in registers; no further barriers
  if (tid < T) {
    double q[32];
#pragma unroll
    for (int k = 0; k < 32; ++k) q[k] = Ps[tid][k];
#pragma unroll
    for (int j = 0; j < 32; ++j) {
      double s = q[j];
#pragma unroll
      for (int k = 0; k < 32; ++k)
        if (k < j) s -= q[k] * L11s[j][k];
      q[j] = s * rpivs[j];
    }
    double* dst = &A[(size_t)(j0 + 32 + tid) * DD + j0];
#pragma unroll
    for (int k = 0; k < 32; ++k) dst[k] = q[k];
  }
}

// ---------------------------------------------------------------------------
// K4b: trailing update A22 -= L21 * L21^T for panel kb, one 64x64 tile per
// block (lower tiles only), massively parallel: grid = 64 matrices x ntiles.
// ---------------------------------------------------------------------------
__global__ __launch_bounds__(256) void k_trail(double* __restrict__ cov,
                                               int kb) {
  const int b = blockIdx.x;
  double* A = cov + (size_t)b * DD * DD;
  const int j0 = kb * 32;
  const int T = DD - j0 - 32;
  // map linear tile index -> (tI, tJ), tI >= tJ
  int tI = 0, tJ = (int)blockIdx.y;
  while (tJ > tI) {
    tJ -= (tI + 1);
    tI++;
  }
  const int i0 = tI * 64, jj0 = tJ * 64;
  const int tid = threadIdx.x;
  const int tx = tid & 15, ty = tid >> 4;

  __shared__ double Ea[64][33];
  __shared__ double Eb[64][33];

  // stage the two L21 strips (rows i0..i0+63 and jj0..jj0+63), zero-padded
  for (int e = tid; e < 64 * 32; e += 256) {
    int r = e >> 5, c = e & 31;
    Ea[r][c] = (i0 + r < T)
                   ? A[(size_t)(j0 + 32 + i0 + r) * DD + j0 + c]
                   : 0.0;
    Eb[r][c] = (jj0 + r < T)
                   ? A[(size_t)(j0 + 32 + jj0 + r) * DD + j0 + c]
                   : 0.0;
  }
  __syncthreads();

  double s[4][4];
#pragma unroll
  for (int i = 0; i < 4; ++i)
#pragma unroll
    for (int j = 0; j < 4; ++j) s[i][j] = 0.0;

  const int bi = ty * 4, bj = tx * 4;
#pragma unroll
  for (int k = 0; k < 32; ++k) {
    double a[4], bv[4];
#pragma unroll
    for (int i = 0; i < 4; ++i) a[i] = Ea[bi + i][k];
#pragma unroll
    for (int j = 0; j < 4; ++j) bv[j] = Eb[bj + j][k];
#pragma unroll
    for (int i = 0; i < 4; ++i)
#pragma unroll
      for (int j = 0; j < 4; ++j) s[i][j] = fma(a[i], bv[j], s[i][j]);
  }

#pragma unroll
  for (int i = 0; i < 4; ++i)
#pragma unroll
    for (int j = 0; j < 4; ++j) {
      int gi = i0 + bi + i, gj = jj0 + bj + j;
      if (gi < T && gj < T && gi >= gj)
        A[(size_t)(j0 + 32 + gi) * DD + (j0 + 32 + gj)] -= s[i][j];
    }
}

// ---------------------------------------------------------------------------
// K5: out[b, triu(i,j)] = (i==j) ? 2*log(L[ii]) : L[j][i], fp32.
// ---------------------------------------------------------------------------
__global__ __launch_bounds__(256) void k_out(const double* __restrict__ cov,
                                             float* __restrict__ out) {
  const int b = blockIdx.y;
  const int ij = blockIdx.x * 256 + threadIdx.x;
  const int i = ij >> 8, j = ij & 255;
  if (j < i) return;
  const double* A = cov + (size_t)b * DD * DD;
  double v;
  if (i == j)
    v = 2.0 * log(A[(size_t)i * DD + i]);
  else
    v = A[(size_t)j * DD + i];
  const int off = i * DD - (i * (i - 1)) / 2 + (j - i);
  out[(size_t)b * 32896 + off] = (float)v;
}

extern "C" void kernel_launch(void* const* d_in, const int* in_sizes, int n_in,
                              void* d_out, int out_size, void* d_ws,
                              size_t ws_size, hipStream_t stream) {
  const float* x = (const float*)d_in[0];
  const float* w = (const float*)d_in[1];
  const float* gamma = (const float*)d_in[2];
  const float* beta = (const float*)d_in[3];
  const float* rmean = (const float*)d_in[4];
  const float* rvar = (const float*)d_in[5];
  float* out = (float*)d_out;

  char* ws = (char*)d_ws;
  float* yt = (float*)ws;                           // 64*196*256*4 = 12,845,056 B
  double* mean = (double*)(ws + 12845056);          // 64*256*8     =    131,072 B
  double* cov = (double*)(ws + 12845056 + 131072);  // 64*256*256*8 = 33,554,432 B

  k_conv<<<dim3(NTOT / 128, DD / 128), 256, 0, stream>>>(x, w, gamma, beta,
                                                         rmean, rvar, yt);
  k_means<<<BB, 256, 0, stream>>>(yt, mean);
  k_cov<<<dim3(BB, 10), 256, 0, stream>>>(yt, mean, cov);
  for (int kb = 0; kb < 8; ++kb) {
    k_panel<<<BB, 256, 0, stream>>>(cov, kb);
    int T = DD - kb * 32 - 32;
    if (T > 0) {
      int nt = (T + 63) / 64;
      int ntiles = nt * (nt + 1) / 2;
      k_trail<<<dim3(BB, ntiles), 256, 0, stream>>>(cov, kb);
    }
  }
  k_out<<<dim3(DD * DD / 256, BB), 256, 0, stream>>>(cov, out);
}